// Round 7
// baseline (101.224 us; speedup 1.0000x reference)
//
#include <hip/hip_runtime.h>

typedef unsigned short u16;
typedef unsigned int   u32;
typedef u16   u16x8 __attribute__((ext_vector_type(8)));
typedef float f32x4 __attribute__((ext_vector_type(4)));
typedef __bf16 bf16x8 __attribute__((ext_vector_type(8)));
typedef u32   u32x2 __attribute__((ext_vector_type(2)));
typedef u32   u32x4 __attribute__((ext_vector_type(4)));

#define LOG2E 1.44269504088896f

__device__ __forceinline__ u16 f2bf(float x){
  __bf16 h = (__bf16)x;                 // native v_cvt, RNE
  return __builtin_bit_cast(u16, h);
}

__device__ __forceinline__ f32x4 mfma16x16x32(u16x8 a, u16x8 b, f32x4 c){
  return __builtin_amdgcn_mfma_f32_16x16x32_bf16(
      __builtin_bit_cast(bf16x8, a), __builtin_bit_cast(bf16x8, b), c, 0, 0, 0);
}

// Problem: B=2, Sq=Sk=2048, H=16, D=64, scale = 1/8
// q  : f32 [b][t][h][d]    (t-stride 1024, b-stride 2048*1024)
// kv : f32 [b][s][c][h][d] (c-stride 1024, s-stride 2048, b-stride 2048*2048)
// mask: int32 [b][s] ; out: f32 [b][t][h][d]   <-- f32 OUT (round-6 finding)
// Block: 256 thr = 4 waves; block tile = 128 q rows; wave = 32 q rows (2 groups of 16).
// Swapped QK^T: St[key][q]; PV computes O^T[d][q]. KV-tile = 64 keys.
__global__ __launch_bounds__(256, 2)
void attn_fwd(const float* __restrict__ Q, const float* __restrict__ KV,
              const int* __restrict__ MASK, float* __restrict__ OUT)
{
  __shared__ __align__(16) u16 Ksw[64*72];     // K[key][d] bf16, chunk-XOR swizzled
  __shared__ __align__(16) u16 Vsw[64*72];     // V^T[d][s] bf16, chunk-XOR swizzled
  __shared__ __align__(16) u32 Pw[4][32*36];   // per-wave P[q][s] bf16 packed u32

  const int tid  = threadIdx.x;
  const int w    = tid >> 6;
  const int lane = tid & 63;
  const int lg   = lane >> 4;   // lane group 0..3
  const int ln   = lane & 15;

  const int bid = blockIdx.x;
  const int qt  = bid & 15;
  const int h   = (bid >> 4) & 15;
  const int b   = bid >> 8;

  const int qbase = qt*128 + w*32;

  const size_t q_b  = (size_t)b * (2048u*1024u);
  const size_t kv_b = (size_t)b * (2048u*2048u);

  // ---- Q fragments (f32 -> bf16, pre-scaled by 1/8; exact) ----
  // B-frag: lane holds Q[q = ln (+16G)][d = 8*lg + 32*kc + e]
  u16x8 Qf[2][2];
  #pragma unroll
  for (int G = 0; G < 2; ++G){
    const int qrow = qbase + 16*G + ln;
    const float* qp = Q + q_b + (size_t)qrow*1024 + h*64 + 8*lg;
    #pragma unroll
    for (int kc = 0; kc < 2; ++kc){
      f32x4 a = *(const f32x4*)(qp + 32*kc);
      f32x4 c = *(const f32x4*)(qp + 32*kc + 4);
      u16x8 v;
      #pragma unroll
      for (int e = 0; e < 4; ++e){
        v[e]     = f2bf(a[e] * 0.125f);
        v[e + 4] = f2bf(c[e] * 0.125f);
      }
      Qf[G][kc] = v;
    }
  }

  f32x4 Oacc[2][4];   // [G][dt]: O^T rows d = 16*dt + 4*lg + r, col q = ln
  #pragma unroll
  for (int G = 0; G < 2; ++G)
    #pragma unroll
    for (int dt = 0; dt < 4; ++dt)
      Oacc[G][dt] = f32x4{0.f, 0.f, 0.f, 0.f};

  float mrun[2] = { -3.0e38f, -3.0e38f };
  float lrun[2] = { 0.f, 0.f };

  // staging decompositions
  const int s_key = tid >> 2, s_cp = tid & 3;   // K: 4 thr/row, 16 f32 each
  const int s_db  = tid & 7,  s_sp = tid >> 3;  // V: d-block of 8, s-pair

  for (int kt = 0; kt < 32; ++kt){
    const int kb = kt*64;

    // ---- stage K tile: Ksw[key][d], chunk C = d/8, swizzle C ^= (key>>3)&7 ----
    {
      const float* kp = KV + kv_b + (size_t)(kb + s_key)*2048 + h*64 + 16*s_cp;
      f32x4 f0 = *(const f32x4*)(kp);
      f32x4 f1 = *(const f32x4*)(kp + 4);
      f32x4 f2 = *(const f32x4*)(kp + 8);
      f32x4 f3 = *(const f32x4*)(kp + 12);
      u16x8 c0, c1;
      #pragma unroll
      for (int e = 0; e < 4; ++e){
        c0[e] = f2bf(f0[e]); c0[e+4] = f2bf(f1[e]);
        c1[e] = f2bf(f2[e]); c1[e+4] = f2bf(f3[e]);
      }
      const int sw = (s_key >> 3) & 7;
      *(u16x8*)&Ksw[s_key*72 + (((2*s_cp    ) ^ sw) << 3)] = c0;
      *(u16x8*)&Ksw[s_key*72 + (((2*s_cp + 1) ^ sw) << 3)] = c1;
    }
    // ---- stage V tile transposed: Vsw[d][s], chunk C = s/8, swizzle C ^= (d>>3)&7 ----
    {
      const float* vp = KV + kv_b + (size_t)(kb + 2*s_sp)*2048 + 1024 + h*64 + 8*s_db;
      f32x4 r0a = *(const f32x4*)(vp);
      f32x4 r0b = *(const f32x4*)(vp + 4);
      f32x4 r1a = *(const f32x4*)(vp + 2048);
      f32x4 r1b = *(const f32x4*)(vp + 2048 + 4);
      const int swc = ((s_sp >> 2) ^ s_db) << 2;
      #pragma unroll
      for (int j = 0; j < 4; ++j){
        const int d0 = 8*s_db + j;
        const int d1 = d0 + 4;
        const u32 v0 = (u32)f2bf(r0a[j]) | ((u32)f2bf(r1a[j]) << 16);
        const u32 v1 = (u32)f2bf(r0b[j]) | ((u32)f2bf(r1b[j]) << 16);
        ((u32*)Vsw)[d0*36 + swc + (s_sp & 3)] = v0;
        ((u32*)Vsw)[d1*36 + swc + (s_sp & 3)] = v1;
      }
    }
    __syncthreads();

    // ---- QK^T (swapped): St[key][q] ----
    f32x4 S[2][4];   // [G][ct]: keys 16*ct + 4*lg + r, q = ln
    #pragma unroll
    for (int G = 0; G < 2; ++G)
      #pragma unroll
      for (int ct = 0; ct < 4; ++ct)
        S[G][ct] = f32x4{0.f,0.f,0.f,0.f};

    #pragma unroll
    for (int ct = 0; ct < 4; ++ct){
      const int row = 16*ct + ln;
      const int sw  = (row >> 3) & 7;
      #pragma unroll
      for (int kc = 0; kc < 2; ++kc){
        u16x8 kf = *(const u16x8*)&Ksw[row*72 + (((lg + 4*kc) ^ sw) << 3)];
        S[0][ct] = mfma16x16x32(kf, Qf[0][kc], S[0][ct]);
        S[1][ct] = mfma16x16x32(kf, Qf[1][kc], S[1][ct]);
      }
    }

    // ---- key-padding mask: add -10000 to masked keys (int32) ----
    {
      const int* mp = MASK + b*2048 + kb;
      #pragma unroll
      for (int ct = 0; ct < 4; ++ct){
        const int4 mv = *(const int4*)(mp + 16*ct + 4*lg);
        const float a0 = mv.x ? 0.f : -10000.f;
        const float a1 = mv.y ? 0.f : -10000.f;
        const float a2 = mv.z ? 0.f : -10000.f;
        const float a3 = mv.w ? 0.f : -10000.f;
        S[0][ct][0] += a0; S[1][ct][0] += a0;
        S[0][ct][1] += a1; S[1][ct][1] += a1;
        S[0][ct][2] += a2; S[1][ct][2] += a2;
        S[0][ct][3] += a3; S[1][ct][3] += a3;
      }
    }

    // ---- online softmax per group; write P (bf16 packed in u32) to LDS ----
    #pragma unroll
    for (int G = 0; G < 2; ++G){
      float mx = S[G][0][0];
      #pragma unroll
      for (int ct = 0; ct < 4; ++ct)
        #pragma unroll
        for (int r = 0; r < 4; ++r)
          mx = fmaxf(mx, S[G][ct][r]);
      mx = fmaxf(mx, __shfl_xor(mx, 16, 64));
      mx = fmaxf(mx, __shfl_xor(mx, 32, 64));
      const float mnew = fmaxf(mrun[G], mx);
      const float corr = __builtin_amdgcn_exp2f((mrun[G] - mnew) * LOG2E);
      mrun[G] = mnew;

      float ps = 0.f;
      #pragma unroll
      for (int ct = 0; ct < 4; ++ct){
        #pragma unroll
        for (int r = 0; r < 4; ++r){
          const float p = __builtin_amdgcn_exp2f((S[G][ct][r] - mnew) * LOG2E);
          S[G][ct][r] = p;
          ps += p;
        }
      }
      ps += __shfl_xor(ps, 16, 64);
      ps += __shfl_xor(ps, 32, 64);
      lrun[G] = lrun[G]*corr + ps;

      #pragma unroll
      for (int dt = 0; dt < 4; ++dt)
        #pragma unroll
        for (int r = 0; r < 4; ++r)
          Oacc[G][dt][r] *= corr;

      // P row (q = 16G+ln) contiguous along s: one u32x2 per ct.
      #pragma unroll
      for (int ct = 0; ct < 4; ++ct){
        u32x2 pw;
        pw[0] = (u32)f2bf(S[G][ct][0]) | ((u32)f2bf(S[G][ct][1]) << 16);
        pw[1] = (u32)f2bf(S[G][ct][2]) | ((u32)f2bf(S[G][ct][3]) << 16);
        *(u32x2*)&Pw[w][(16*G + ln)*36 + 8*ct + 2*lg] = pw;
      }
    }

    // Compile-time fence: keep P-writes ordered before P-reads (same-wave DS
    // pipe is in-order at HW level; this pins program order for the compiler).
    asm volatile("" ::: "memory");

    // ---- read P fragments (u32-typed, same as writes) ----
    u16x8 Pf[2][2];
    #pragma unroll
    for (int G = 0; G < 2; ++G)
      #pragma unroll
      for (int sc = 0; sc < 2; ++sc){
        u32x4 pr = *(const u32x4*)&Pw[w][(16*G + ln)*36 + 4*lg + 16*sc];
        Pf[G][sc] = __builtin_bit_cast(u16x8, pr);
      }

    // ---- PV: O^T[d][q] += V^T-frag x P-frag ----
    #pragma unroll
    for (int dt = 0; dt < 4; ++dt){
      const int row = 16*dt + ln;
      const int sw  = (row >> 3) & 7;
      #pragma unroll
      for (int sc = 0; sc < 2; ++sc){
        u16x8 vf = *(const u16x8*)&Vsw[row*72 + (((lg + 4*sc) ^ sw) << 3)];
        Oacc[0][dt] = mfma16x16x32(vf, Pf[0][sc], Oacc[0][dt]);
        Oacc[1][dt] = mfma16x16x32(vf, Pf[1][sc], Oacc[1][dt]);
      }
    }
    __syncthreads();
  }

  // ---- epilogue: normalize and store as FLOAT32 ----
  #pragma unroll
  for (int G = 0; G < 2; ++G){
    const float inv = 1.f / lrun[G];
    const int qrow = qbase + 16*G + ln;
    float* op = OUT + q_b + (size_t)qrow*1024 + h*64;
    #pragma unroll
    for (int dt = 0; dt < 4; ++dt){
      f32x4 ov;
      ov[0] = Oacc[G][dt][0] * inv;
      ov[1] = Oacc[G][dt][1] * inv;
      ov[2] = Oacc[G][dt][2] * inv;
      ov[3] = Oacc[G][dt][3] * inv;
      *(f32x4*)(op + 16*dt + 4*lg) = ov;   // d = 16*dt + 4*lg + r, 16B aligned
    }
  }
}

extern "C" void kernel_launch(void* const* d_in, const int* in_sizes, int n_in,
                              void* d_out, int out_size, void* d_ws, size_t ws_size,
                              hipStream_t stream)
{
  // q = 4194304, kv = 8388608, mask = 4096 (element counts); fallback positional.
  const float* Q  = nullptr;
  const float* KV = nullptr;
  const int*   M  = nullptr;
  for (int i = 0; i < n_in; ++i){
    if      (in_sizes[i] == 4194304) Q  = (const float*)d_in[i];
    else if (in_sizes[i] == 8388608) KV = (const float*)d_in[i];
    else if (in_sizes[i] == 4096)    M  = (const int*)d_in[i];
  }
  if (!Q)  Q  = (const float*)d_in[0];
  if (!KV) KV = (const float*)d_in[1];
  if (!M)  M  = (const int*)d_in[2];
  float* O = (float*)d_out;
  attn_fwd<<<dim3(512), dim3(256), 0, stream>>>(Q, KV, M, O);
}

// Round 8
// 84.482 us; speedup vs baseline: 1.1982x; 1.1982x over previous
//
#include <hip/hip_runtime.h>

typedef unsigned short u16;
typedef unsigned int   u32;
typedef u16   u16x8 __attribute__((ext_vector_type(8)));
typedef float f32x4 __attribute__((ext_vector_type(4)));
typedef __bf16 bf16x8 __attribute__((ext_vector_type(8)));
typedef u32   u32x2 __attribute__((ext_vector_type(2)));
typedef u32   u32x4 __attribute__((ext_vector_type(4)));

#define LOG2E 1.44269504088896f
#define RTHR  5.545177444479562f   // 8*ln2: defer-rescale threshold (P <= 2^8)

__device__ __forceinline__ u16 f2bf(float x){
  __bf16 h = (__bf16)x;
  return __builtin_bit_cast(u16, h);
}

__device__ __forceinline__ f32x4 mfma16x16x32(u16x8 a, u16x8 b, f32x4 c){
  return __builtin_amdgcn_mfma_f32_16x16x32_bf16(
      __builtin_bit_cast(bf16x8, a), __builtin_bit_cast(bf16x8, b), c, 0, 0, 0);
}

// ===================== pre-pass: f32 KV -> swizzled bf16 tile image ==========
// IMG layout: per (b,h,kt): 9216 u16 = [K image 4608 u16 | V image 4608 u16]
//  K image: row=key (stride 72), 16B chunk C=d/8, C ^= (key>>3)&7
//  V image: row=d   (stride 72=36 u32), u32=(s,s+1) pair, chunk C=s/8, C ^= (d>>3)&7
__global__ __launch_bounds__(256, 4)
void prepass(const float* __restrict__ KV, const int* __restrict__ MASK,
             u16* __restrict__ IMG, float* __restrict__ BIAS)
{
  const int tid = threadIdx.x;
  const int bid = blockIdx.x;        // ((b*16+h)*32 + kt)
  const int kt = bid & 31;
  const int h  = (bid >> 5) & 15;
  const int b  = bid >> 9;
  const int kb = kt*64;
  const size_t kv_b = (size_t)b*(2048u*2048u);
  u16* tile = IMG + (size_t)bid * 9216;

  // ---- K image ----
  {
    const int skey = tid >> 2, scp = tid & 3;
    const float* kp = KV + kv_b + (size_t)(kb + skey)*2048 + h*64 + 16*scp;
    f32x4 f0 = *(const f32x4*)(kp);
    f32x4 f1 = *(const f32x4*)(kp + 4);
    f32x4 f2 = *(const f32x4*)(kp + 8);
    f32x4 f3 = *(const f32x4*)(kp + 12);
    u16x8 c0, c1;
    #pragma unroll
    for (int e = 0; e < 4; ++e){
      c0[e] = f2bf(f0[e]); c0[e+4] = f2bf(f1[e]);
      c1[e] = f2bf(f2[e]); c1[e+4] = f2bf(f3[e]);
    }
    const int sw = (skey >> 3) & 7;
    *(u16x8*)&tile[skey*72 + (((2*scp    ) ^ sw) << 3)] = c0;
    *(u16x8*)&tile[skey*72 + (((2*scp + 1) ^ sw) << 3)] = c1;
  }
  // ---- V image (transposed) ----
  {
    const int sdb = tid & 7, ssp = tid >> 3;
    const float* vp = KV + kv_b + (size_t)(kb + 2*ssp)*2048 + 1024 + h*64 + 8*sdb;
    f32x4 r0a = *(const f32x4*)(vp);
    f32x4 r0b = *(const f32x4*)(vp + 4);
    f32x4 r1a = *(const f32x4*)(vp + 2048);
    f32x4 r1b = *(const f32x4*)(vp + 2048 + 4);
    u32* vimg = (u32*)(tile + 4608);
    const int swc = ((ssp >> 2) ^ sdb) << 2;
    #pragma unroll
    for (int j = 0; j < 4; ++j){
      const int d0 = 8*sdb + j;
      const int d1 = d0 + 4;
      vimg[d0*36 + swc + (ssp & 3)] = (u32)f2bf(r0a[j]) | ((u32)f2bf(r1a[j]) << 16);
      vimg[d1*36 + swc + (ssp & 3)] = (u32)f2bf(r0b[j]) | ((u32)f2bf(r1b[j]) << 16);
    }
  }
  // ---- mask -> additive f32 bias ----
  if (h == 0 && tid < 64){
    const int s = kb + tid;
    BIAS[b*2048 + s] = MASK[b*2048 + s] ? 0.f : -10000.f;
  }
}

// ===================== main: MFMA flash attention ============================
// PRE=1: stage from bf16 IMG (pure 16B copy). PRE=0: stage from f32 KV (cvt in kernel).
// Pipeline: LDS double-buffer, prefetch loads issued before compute, 1 barrier/tile.
template<int PRE>
__global__ __launch_bounds__(256, 2)
void attn_main(const float* __restrict__ Q, const float* __restrict__ KV,
               const int* __restrict__ MASK, const u16* __restrict__ IMG,
               const float* __restrict__ BIAS, float* __restrict__ OUT)
{
  __shared__ __align__(16) u16 KVbuf[2][9216];   // [K 4608 u16 | V 4608 u16] x dbuf
  __shared__ __align__(16) u32 Pw[4][32*36];     // per-wave P[q][s] bf16 packed u32

  const int tid  = threadIdx.x;
  const int w    = tid >> 6;
  const int lane = tid & 63;
  const int lg   = lane >> 4;
  const int ln   = lane & 15;

  // XCD-aware swizzle: group the 16 qt-blocks of one (b,h) on one XCD
  const int bid0 = blockIdx.x;
  const int bid  = (bid0 & 7)*64 + (bid0 >> 3);
  const int qt  = bid & 15;
  const int h   = (bid >> 4) & 15;
  const int b   = bid >> 8;

  const int qbase = qt*128 + w*32;
  const size_t q_b  = (size_t)b * (2048u*1024u);
  const size_t kv_b = (size_t)b * (2048u*2048u);

  // ---- Q fragments (f32 -> bf16, pre-scaled by 1/8; exact) ----
  u16x8 Qf[2][2];
  #pragma unroll
  for (int G = 0; G < 2; ++G){
    const int qrow = qbase + 16*G + ln;
    const float* qp = Q + q_b + (size_t)qrow*1024 + h*64 + 8*lg;
    #pragma unroll
    for (int kc = 0; kc < 2; ++kc){
      f32x4 a = *(const f32x4*)(qp + 32*kc);
      f32x4 c = *(const f32x4*)(qp + 32*kc + 4);
      u16x8 v;
      #pragma unroll
      for (int e = 0; e < 4; ++e){
        v[e]     = f2bf(a[e] * 0.125f);
        v[e + 4] = f2bf(c[e] * 0.125f);
      }
      Qf[G][kc] = v;
    }
  }

  f32x4 Oacc[2][4];
  #pragma unroll
  for (int G = 0; G < 2; ++G)
    #pragma unroll
    for (int dt = 0; dt < 4; ++dt)
      Oacc[G][dt] = f32x4{0.f, 0.f, 0.f, 0.f};

  float mrun[2] = { -3.0e38f, -3.0e38f };
  float lrun[2] = { 0.f, 0.f };

  // staging constants
  const int skey = tid >> 2, scp = tid & 3;   // PRE=0 K
  const int sdb  = tid & 7,  ssp = tid >> 3;  // PRE=0 V
  const int swk  = (skey >> 3) & 7;
  const int swc  = ((ssp >> 2) ^ sdb) << 2;
  const float* kp0 = KV + kv_b + (size_t)skey*2048 + h*64 + 16*scp;
  const float* vp0 = KV + kv_b + (size_t)(2*ssp)*2048 + 1024 + h*64 + 8*sdb;
  const u32x4* gt0 = (const u32x4*)IMG + (size_t)((b*16 + h)*32) * 1152; // 1152 u32x4/tile

  // staging registers (unused set is dead-code-eliminated per PRE)
  u32x4 creg[5];
  f32x4 kf0, kf1, kf2, kf3, va, vb2, vc, vd;

  // ---- stage tile 0 ----
  if constexpr (PRE){
    const u32x4* gp = gt0;
    #pragma unroll
    for (int i = 0; i < 4; ++i) creg[i] = gp[tid + (i << 8)];
    if (tid < 128) creg[4] = gp[1024 + tid];
    u32x4* lp = (u32x4*)&KVbuf[0][0];
    #pragma unroll
    for (int i = 0; i < 4; ++i) lp[tid + (i << 8)] = creg[i];
    if (tid < 128) lp[1024 + tid] = creg[4];
  } else {
    const float* kp = kp0;
    kf0 = *(const f32x4*)(kp); kf1 = *(const f32x4*)(kp+4);
    kf2 = *(const f32x4*)(kp+8); kf3 = *(const f32x4*)(kp+12);
    const float* vp = vp0;
    va = *(const f32x4*)(vp); vb2 = *(const f32x4*)(vp+4);
    vc = *(const f32x4*)(vp+2048); vd = *(const f32x4*)(vp+2048+4);
    u16x8 c0, c1;
    #pragma unroll
    for (int e = 0; e < 4; ++e){
      c0[e] = f2bf(kf0[e]); c0[e+4] = f2bf(kf1[e]);
      c1[e] = f2bf(kf2[e]); c1[e+4] = f2bf(kf3[e]);
    }
    *(u16x8*)&KVbuf[0][skey*72 + (((2*scp  )^swk)<<3)] = c0;
    *(u16x8*)&KVbuf[0][skey*72 + (((2*scp+1)^swk)<<3)] = c1;
    u32* vimg = (u32*)&KVbuf[0][4608];
    #pragma unroll
    for (int j = 0; j < 4; ++j){
      const int d0 = 8*sdb + j, d1 = d0 + 4;
      vimg[d0*36 + swc + (ssp&3)] = (u32)f2bf(va[j])  | ((u32)f2bf(vc[j]) << 16);
      vimg[d1*36 + swc + (ssp&3)] = (u32)f2bf(vb2[j]) | ((u32)f2bf(vd[j]) << 16);
    }
  }
  __syncthreads();

  int cur = 0;
  for (int kt = 0; kt < 32; ++kt){
    const int kb = kt*64;

    // ---- issue prefetch loads for tile kt+1 (land during compute) ----
    if (kt < 31){
      if constexpr (PRE){
        const u32x4* gp = gt0 + (size_t)(kt+1)*1152;
        #pragma unroll
        for (int i = 0; i < 4; ++i) creg[i] = gp[tid + (i << 8)];
        if (tid < 128) creg[4] = gp[1024 + tid];
      } else {
        const float* kp = kp0 + (size_t)(kt+1)*64*2048;
        kf0 = *(const f32x4*)(kp); kf1 = *(const f32x4*)(kp+4);
        kf2 = *(const f32x4*)(kp+8); kf3 = *(const f32x4*)(kp+12);
        const float* vp = vp0 + (size_t)(kt+1)*64*2048;
        va = *(const f32x4*)(vp); vb2 = *(const f32x4*)(vp+4);
        vc = *(const f32x4*)(vp+2048); vd = *(const f32x4*)(vp+2048+4);
      }
    }

    const u16* Kb = &KVbuf[cur][0];
    const u16* Vb = &KVbuf[cur][4608];

    // ---- QK^T (swapped): St[key][q] ----
    f32x4 S[2][4];
    #pragma unroll
    for (int G = 0; G < 2; ++G)
      #pragma unroll
      for (int ct = 0; ct < 4; ++ct)
        S[G][ct] = f32x4{0.f,0.f,0.f,0.f};

    #pragma unroll
    for (int ct = 0; ct < 4; ++ct){
      const int row = 16*ct + ln;
      const int sw  = (row >> 3) & 7;
      #pragma unroll
      for (int kc = 0; kc < 2; ++kc){
        u16x8 kfr = *(const u16x8*)&Kb[row*72 + (((lg + 4*kc) ^ sw) << 3)];
        S[0][ct] = mfma16x16x32(kfr, Qf[0][kc], S[0][ct]);
        S[1][ct] = mfma16x16x32(kfr, Qf[1][kc], S[1][ct]);
      }
    }

    // ---- additive mask bias ----
    #pragma unroll
    for (int ct = 0; ct < 4; ++ct){
      float a0, a1, a2, a3;
      if constexpr (PRE){
        const f32x4 bv = *(const f32x4*)(BIAS + b*2048 + kb + 16*ct + 4*lg);
        a0 = bv[0]; a1 = bv[1]; a2 = bv[2]; a3 = bv[3];
      } else {
        const int4 mv = *(const int4*)(MASK + b*2048 + kb + 16*ct + 4*lg);
        a0 = mv.x ? 0.f : -10000.f;
        a1 = mv.y ? 0.f : -10000.f;
        a2 = mv.z ? 0.f : -10000.f;
        a3 = mv.w ? 0.f : -10000.f;
      }
      S[0][ct][0] += a0; S[1][ct][0] += a0;
      S[0][ct][1] += a1; S[1][ct][1] += a1;
      S[0][ct][2] += a2; S[1][ct][2] += a2;
      S[0][ct][3] += a3; S[1][ct][3] += a3;
    }

    // ---- online softmax (defer-rescale, fma-folded exp2) ----
    #pragma unroll
    for (int G = 0; G < 2; ++G){
      float mx = S[G][0][0];
      #pragma unroll
      for (int ct = 0; ct < 4; ++ct)
        #pragma unroll
        for (int r = 0; r < 4; ++r)
          mx = fmaxf(mx, S[G][ct][r]);
      mx = fmaxf(mx, __shfl_xor(mx, 16, 64));
      mx = fmaxf(mx, __shfl_xor(mx, 32, 64));

      if (__any(mx > mrun[G] + RTHR)){
        const float mnew = fmaxf(mrun[G], mx);
        const float corr = __builtin_amdgcn_exp2f((mrun[G] - mnew) * LOG2E);
        mrun[G] = mnew;
        lrun[G] *= corr;
        #pragma unroll
        for (int dt = 0; dt < 4; ++dt)
          #pragma unroll
          for (int r = 0; r < 4; ++r)
            Oacc[G][dt][r] *= corr;
      }
      const float mc = mrun[G] * LOG2E;

      float ps = 0.f;
      #pragma unroll
      for (int ct = 0; ct < 4; ++ct){
        #pragma unroll
        for (int r = 0; r < 4; ++r){
          const float p = __builtin_amdgcn_exp2f(__builtin_fmaf(S[G][ct][r], LOG2E, -mc));
          S[G][ct][r] = p;
          ps += p;
        }
      }
      ps += __shfl_xor(ps, 16, 64);
      ps += __shfl_xor(ps, 32, 64);
      lrun[G] += ps;

      #pragma unroll
      for (int ct = 0; ct < 4; ++ct){
        u32x2 pw;
        pw[0] = (u32)f2bf(S[G][ct][0]) | ((u32)f2bf(S[G][ct][1]) << 16);
        pw[1] = (u32)f2bf(S[G][ct][2]) | ((u32)f2bf(S[G][ct][3]) << 16);
        *(u32x2*)&Pw[w][(16*G + ln)*36 + 8*ct + 2*lg] = pw;
      }
    }

    asm volatile("" ::: "memory");   // pin P write->read program order (same-wave DS)

    u16x8 Pf[2][2];
    #pragma unroll
    for (int G = 0; G < 2; ++G)
      #pragma unroll
      for (int sc = 0; sc < 2; ++sc){
        u32x4 pr = *(const u32x4*)&Pw[w][(16*G + ln)*36 + 4*lg + 16*sc];
        Pf[G][sc] = __builtin_bit_cast(u16x8, pr);
      }

    // ---- PV: O^T[d][q] += V^T-frag x P-frag ----
    #pragma unroll
    for (int dt = 0; dt < 4; ++dt){
      const int row = 16*dt + ln;
      const int sw  = (row >> 3) & 7;
      #pragma unroll
      for (int sc = 0; sc < 2; ++sc){
        u16x8 vf = *(const u16x8*)&Vb[row*72 + (((lg + 4*sc) ^ sw) << 3)];
        Oacc[0][dt] = mfma16x16x32(vf, Pf[0][sc], Oacc[0][dt]);
        Oacc[1][dt] = mfma16x16x32(vf, Pf[1][sc], Oacc[1][dt]);
      }
    }

    // ---- write prefetched tile kt+1 into the other buffer; single barrier ----
    if (kt < 31){
      const int nxt = cur ^ 1;
      if constexpr (PRE){
        u32x4* lp = (u32x4*)&KVbuf[nxt][0];
        #pragma unroll
        for (int i = 0; i < 4; ++i) lp[tid + (i << 8)] = creg[i];
        if (tid < 128) lp[1024 + tid] = creg[4];
      } else {
        u16x8 c0, c1;
        #pragma unroll
        for (int e = 0; e < 4; ++e){
          c0[e] = f2bf(kf0[e]); c0[e+4] = f2bf(kf1[e]);
          c1[e] = f2bf(kf2[e]); c1[e+4] = f2bf(kf3[e]);
        }
        *(u16x8*)&KVbuf[nxt][skey*72 + (((2*scp  )^swk)<<3)] = c0;
        *(u16x8*)&KVbuf[nxt][skey*72 + (((2*scp+1)^swk)<<3)] = c1;
        u32* vimg = (u32*)&KVbuf[nxt][4608];
        #pragma unroll
        for (int j = 0; j < 4; ++j){
          const int d0 = 8*sdb + j, d1 = d0 + 4;
          vimg[d0*36 + swc + (ssp&3)] = (u32)f2bf(va[j])  | ((u32)f2bf(vc[j]) << 16);
          vimg[d1*36 + swc + (ssp&3)] = (u32)f2bf(vb2[j]) | ((u32)f2bf(vd[j]) << 16);
        }
      }
      __syncthreads();
      cur ^= 1;
    }
  }

  // ---- epilogue: normalize and store f32 ----
  #pragma unroll
  for (int G = 0; G < 2; ++G){
    const float inv = 1.f / lrun[G];
    const int qrow = qbase + 16*G + ln;
    float* op = OUT + q_b + (size_t)qrow*1024 + h*64;
    #pragma unroll
    for (int dt = 0; dt < 4; ++dt){
      f32x4 ov;
      ov[0] = Oacc[G][dt][0] * inv;
      ov[1] = Oacc[G][dt][1] * inv;
      ov[2] = Oacc[G][dt][2] * inv;
      ov[3] = Oacc[G][dt][3] * inv;
      *(f32x4*)(op + 16*dt + 4*lg) = ov;
    }
  }
}

extern "C" void kernel_launch(void* const* d_in, const int* in_sizes, int n_in,
                              void* d_out, int out_size, void* d_ws, size_t ws_size,
                              hipStream_t stream)
{
  const float* Q  = nullptr;
  const float* KV = nullptr;
  const int*   M  = nullptr;
  for (int i = 0; i < n_in; ++i){
    if      (in_sizes[i] == 4194304) Q  = (const float*)d_in[i];
    else if (in_sizes[i] == 8388608) KV = (const float*)d_in[i];
    else if (in_sizes[i] == 4096)    M  = (const int*)d_in[i];
  }
  if (!Q)  Q  = (const float*)d_in[0];
  if (!KV) KV = (const float*)d_in[1];
  if (!M)  M  = (const int*)d_in[2];
  float* O = (float*)d_out;

  const size_t NEED = 16384ull + 1024ull*18432ull;   // bias + KV image = 18.9 MB
  if (ws_size >= NEED){
    float* bias = (float*)d_ws;
    u16*   img  = (u16*)((char*)d_ws + 16384);
    prepass<<<dim3(1024), dim3(256), 0, stream>>>(KV, M, img, bias);
    attn_main<1><<<dim3(512), dim3(256), 0, stream>>>(Q, KV, M, img, bias, O);
  } else {
    attn_main<0><<<dim3(512), dim3(256), 0, stream>>>(Q, KV, M, nullptr, nullptr, O);
  }
}